// Round 1
// 125.264 us; speedup vs baseline: 1.5659x; 1.5659x over previous
//
#include <hip/hip_runtime.h>
#include <hip/hip_bf16.h>
#include <math.h>

#define HF 32
#define WF 88
#define NCAM 6
#define CC 128
#define ZD 128
#define YD 8
#define XD 128

using f32x4  = __attribute__((ext_vector_type(4))) float;
using bf16x8 = __attribute__((ext_vector_type(8))) short;

// ---- workspace layout (bytes) ----
#define OFF_P    0ull
#define OFF_W    512ull                        // Wp: 9*131072*2 = 2359296
#define OFF_CAMT (OFF_W + 2359296ull)          // camT: 6*32*88*128*4 = 8650752 (reused as conv1 after k2)
#define OFF_F    (OFF_CAMT + 8650752ull)       // Fpack: 130*130*1024*2 = 34611200
#define OFF_CONV (OFF_F + 34611200ull)         // conv partial 0: 128*16384*4 = 8388608

// ============ K0: camera matrices ============
__global__ __launch_bounds__(64) void k0_mats(const float* __restrict__ cam2ego,
                                              const float* __restrict__ intr,
                                              float* __restrict__ P) {
  int s = threadIdx.x;
  if (s >= NCAM) return;
  const float* M0 = cam2ego;
  const float* Ms = cam2ego + s * 16;
  float Rb[9], tb[3];
  for (int i = 0; i < 3; i++)
    for (int j = 0; j < 3; j++) {
      float v = 0.f;
      for (int k = 0; k < 3; k++) v += Ms[k * 4 + i] * M0[k * 4 + j];
      Rb[i * 3 + j] = v;
    }
  for (int i = 0; i < 3; i++) {
    float v = 0.f;
    for (int k = 0; k < 3; k++) v += Ms[k * 4 + i] * (M0[k * 4 + 3] - Ms[k * 4 + 3]);
    tb[i] = v;
  }
  const float* Ks = intr + s * 16;
  const float sx = (float)WF / 704.0f * 0.44f;
  const float sy = (float)HF / 256.0f * 0.284f;
  const float fx = Ks[0] * sx, fy = Ks[5] * sy;
  const float cx = Ks[2] * sx, cy = Ks[6] * sy;
  float* p = P + s * 12;
  for (int j = 0; j < 3; j++) p[j]     = fx * Rb[j]     + cx * Rb[6 + j];
  p[3]  = fx * tb[0] + cx * tb[2];
  for (int j = 0; j < 3; j++) p[4 + j] = fy * Rb[3 + j] + cy * Rb[6 + j];
  p[7]  = fy * tb[1] + cy * tb[2];
  for (int j = 0; j < 3; j++) p[8 + j] = Rb[6 + j];
  p[11] = tb[2];
}

// ============ K1: cam_feat (S,C,H,W) -> camT (S,H,W,C) ============
__global__ __launch_bounds__(128) void k1_transpose(const float* __restrict__ feat,
                                                    float* __restrict__ camT) {
  const int b = blockIdx.x;
  const int wq = b & 3;
  const int sh = b >> 2;
  const int c = threadIdx.x;
  const float* src = feat + ((size_t)(sh / HF) * CC + c) * (HF * WF) + (sh % HF) * WF + wq * 22;
  float* dst = camT + ((size_t)sh * WF + wq * 22) * CC + c;
  for (int w = 0; w < 22; w++) dst[w * CC] = src[w];
}

// ============ K1b: conv_w (co,ci,3,3) f32 -> Wp[d][co*1024+ci] bf16 ============
__global__ __launch_bounds__(256) void k1b_packw(const float* __restrict__ w,
                                                 __hip_bfloat16* __restrict__ wp) {
  const int t = blockIdx.x * 256 + threadIdx.x;
  float v[9];
  #pragma unroll
  for (int d = 0; d < 9; d++) v[d] = w[(size_t)t * 9 + d];
  #pragma unroll
  for (int d = 0; d < 9; d++) wp[(size_t)d * 131072 + t] = __float2bfloat16(v[d]);
}

// ============ K2: project + bilinear + mask-average -> Fpack (halo-padded) ====
struct Rec { int off[4]; float w[4]; };

__global__ __launch_bounds__(256) void k2_sample(const float* __restrict__ camT,
                                                 const float* __restrict__ P,
                                                 __hip_bfloat16* __restrict__ F) {
  const int bz = blockIdx.x / 130;
  const int bx = blockIdx.x % 130;
  const int t = threadIdx.x;
  const int zi = bz - 1, xi = bx - 1;
  if (zi < 0 || zi >= ZD || xi < 0 || xi >= XD) {
    ushort4 zz; zz.x = 0; zz.y = 0; zz.z = 0; zz.w = 0;
    *reinterpret_cast<ushort4*>(F + (size_t)blockIdx.x * 1024 + t * 4) = zz;
    return;
  }
  __shared__ Rec recs[48];
  if (t < 48) {
    const int y = t / 6, s = t - y * 6;
    const float* pp = P + s * 12;
    const float vx = 100.0f / 128.0f;
    const float xw = xi * vx - 50.0f + vx * 0.5f;
    const float zw = zi * vx - 50.0f + vx * 0.5f;
    const float yw = y * 1.25f - 4.0f + 0.625f;
    const float zc = pp[8] * xw + pp[9] * yw + pp[10] * zw + pp[11];
    const float xp = pp[0] * xw + pp[1] * yw + pp[2] * zw + pp[3];
    const float yp = pp[4] * xw + pp[5] * yw + pp[6] * zw + pp[7];
    const float dep = fmaxf(zc, 1e-4f);
    const float pxf = xp / dep, pyf = yp / dep;
    const bool valid = (pxf > -0.5f && pxf < (float)WF - 0.5f &&
                        pyf > -0.5f && pyf < (float)HF - 0.5f && zc > 0.0f);
    const float px = pxf * ((float)WF / (float)(WF - 1)) - 0.5f;
    const float py = pyf * ((float)HF / (float)(HF - 1)) - 0.5f;
    const float fx0 = floorf(px), fy0 = floorf(py);
    const float ddx = px - fx0, ddy = py - fy0;
    const int x0i = (int)fx0, y0i = (int)fy0;
    const float vf = valid ? 1.0f : 0.0f;
    float ww[4];
    ww[0] = (1.0f - ddx) * (1.0f - ddy) * vf;
    ww[1] = ddx * (1.0f - ddy) * vf;
    ww[2] = (1.0f - ddx) * ddy * vf;
    ww[3] = ddx * ddy * vf;
    const int cxs[4] = {x0i, x0i + 1, x0i, x0i + 1};
    const int cys[4] = {y0i, y0i, y0i + 1, y0i + 1};
    Rec r;
    #pragma unroll
    for (int k = 0; k < 4; k++) {
      const bool inb = ((unsigned)cxs[k] < WF) && ((unsigned)cys[k] < HF);
      const int xc = min(max(cxs[k], 0), WF - 1);
      const int yc = min(max(cys[k], 0), HF - 1);
      r.w[k] = inb ? ww[k] : 0.0f;
      r.off[k] = (s * (HF * WF) + yc * WF + xc) * CC;
    }
    recs[t] = r;
  }
  __syncthreads();

  const int c = t & 127;
  const int yh = t >> 7;
  float num[4] = {0.f, 0.f, 0.f, 0.f};
  float den[4] = {0.f, 0.f, 0.f, 0.f};
  #pragma unroll
  for (int yi = 0; yi < 4; yi++) {
    const int y = yh * 4 + yi;
    for (int s = 0; s < NCAM; s++) {
      const Rec r = recs[y * 6 + s];
      if (r.w[0] == 0.f && r.w[1] == 0.f && r.w[2] == 0.f && r.w[3] == 0.f) continue;
      const float v = r.w[0] * camT[r.off[0] + c] + r.w[1] * camT[r.off[1] + c] +
                      r.w[2] * camT[r.off[2] + c] + r.w[3] * camT[r.off[3] + c];
      num[yi] += v;
      den[yi] += (v != 0.0f) ? 1.0f : 0.0f;
    }
  }
  __hip_bfloat16 hb[4];
  #pragma unroll
  for (int i = 0; i < 4; i++) hb[i] = __float2bfloat16(num[i] / (1e-6f + den[i]));
  *reinterpret_cast<ushort4*>(F + (size_t)blockIdx.x * 1024 + c * 8 + yh * 4) =
      *reinterpret_cast<const ushort4*>(hb);
}

// ============ K3: implicit-GEMM 3x3 conv, bf16 MFMA ============
// v2: 128x128 tile, BK=64, split-K=2 by ci-halves (NO atomics — plain f32x4
// stores to 2 partial buffers, fused reduce in k4). grid 256 = 1 block/CU,
// 512 threads = 8 waves. 4-deep LDS ring (128 KB), counted vmcnt.
__device__ __forceinline__ void load_lds16(const void* g, void* l) {
  __builtin_amdgcn_global_load_lds(
      (const __attribute__((address_space(1))) unsigned int*)g,
      (__attribute__((address_space(3))) unsigned int*)l, 16, 0, 0);
}

#define K3_NT 72   // 9 taps * 8 ci-chunks (ci-half of 512, BK=64)

__global__ __launch_bounds__(512) void k3_gemm(const __hip_bfloat16* __restrict__ F,
                                               const __hip_bfloat16* __restrict__ Wp,
                                               float* __restrict__ out0,
                                               float* __restrict__ out1) {
  // XCD-aware swizzle: 32 consecutive logical blocks per XCD (256 = 8*32).
  // z = orig&127, h = orig>>7: each XCD works one ci-half over a contiguous
  // 32-z slab -> F working set ~4.5MB + half-Wp 1.2MB per XCD L2.
  const int orig = (blockIdx.x & 7) * 32 + (blockIdx.x >> 3);
  const int z = orig & 127;
  const int h = orig >> 7;          // ci-half: 0 -> ci 0..511, 1 -> 512..1023
  const int ciH = h << 9;
  const int tid = threadIdx.x;
  const int w = tid >> 6;           // wave 0..7
  const int l = tid & 63;
  const int wm = w >> 2;            // 0..1  (64 x-rows each)
  const int wn = w & 3;             // 0..3  (32 co each)
  __shared__ __hip_bfloat16 lds[4][16384];  // ring: A[128][64] + B[128][64] per stage (32KB)

  f32x4 acc[4][2];
  #pragma unroll
  for (int m = 0; m < 4; m++)
    #pragma unroll
    for (int n = 0; n < 2; n++)
      acc[m][n] = (f32x4){0.f, 0.f, 0.f, 0.f};

  auto stage = [&](int kt) {
    const int buf = kt & 3;
    const int d = kt >> 3;                    // tap 0..8
    const int dz = d / 3, dx = d - dz * 3;
    const int ci0 = ciH + ((kt & 7) << 6);
    const int zbase = (z + dz) * 130 + dx;
    // A: 128 x-rows x 64 ci = 1024 x 16B chunks; chunk n -> (row=n>>3, slot=n&7)
    // content at (row,slot) = ci-chunk (slot ^ (row&7))  [XOR swizzle]
    #pragma unroll
    for (int i = 0; i < 2; i++) {
      const int n = w * 128 + i * 64 + l;
      const int row = n >> 3;
      const int q = (n & 7) ^ (row & 7);
      const __hip_bfloat16* src = F + ((size_t)(zbase + row) << 10) + ci0 + (q << 3);
      load_lds16(src, &lds[buf][(w * 128 + i * 64) * 8]);
    }
    // B: 128 co x 64 ci, same swizzle
    #pragma unroll
    for (int i = 0; i < 2; i++) {
      const int n = w * 128 + i * 64 + l;
      const int co = n >> 3;
      const int q = (n & 7) ^ (co & 7);
      const __hip_bfloat16* src = Wp + ((size_t)d << 17) + ((size_t)co << 10) + ci0 + (q << 3);
      load_lds16(src, &lds[buf][8192 + (w * 128 + i * 64) * 8]);
    }
  };

  auto compute = [&](int kt) {
    const int buf = kt & 3;
    const int r16 = l & 15;
    const int hi = l >> 4;
    #pragma unroll
    for (int kk = 0; kk < 2; kk++) {
      const int c = kk * 4 + hi;              // 16B ci-chunk 0..7
      bf16x8 a[4], b[2];
      #pragma unroll
      for (int m = 0; m < 4; m++) {
        const int r = wm * 64 + m * 16 + r16;
        const int slot = c ^ (r & 7);
        a[m] = *reinterpret_cast<const bf16x8*>(&lds[buf][r * 64 + slot * 8]);
      }
      #pragma unroll
      for (int n = 0; n < 2; n++) {
        const int co = wn * 32 + n * 16 + r16;
        const int slot = c ^ (co & 7);
        b[n] = *reinterpret_cast<const bf16x8*>(&lds[buf][8192 + co * 64 + slot * 8]);
      }
      #pragma unroll
      for (int m = 0; m < 4; m++)
        #pragma unroll
        for (int n = 0; n < 2; n++)
          acc[m][n] = __builtin_amdgcn_mfma_f32_16x16x32_bf16(a[m], b[n], acc[m][n], 0, 0, 0);
    }
  };

  // prologue: 3 stages in flight (12 outstanding loads/wave)
  stage(0); stage(1); stage(2);

  // main loop: wait only for oldest stage (vmcnt 8 = 2 stages still in flight)
  for (int t = 0; t < K3_NT - 2; ++t) {
    asm volatile("s_waitcnt vmcnt(8)" ::: "memory");
    __builtin_amdgcn_s_barrier();
    if (t + 3 < K3_NT) stage(t + 3);
    compute(t);
  }
  asm volatile("s_waitcnt vmcnt(4)" ::: "memory");
  __builtin_amdgcn_s_barrier();
  compute(K3_NT - 2);
  asm volatile("s_waitcnt vmcnt(0)" ::: "memory");
  __builtin_amdgcn_s_barrier();
  compute(K3_NT - 1);

  // epilogue: plain vector stores to this half's partial buffer
  float* outP = h ? out1 : out0;
  const int r16 = l & 15;
  const int hi = l >> 4;
  #pragma unroll
  for (int m = 0; m < 4; m++) {
    const int xr = wm * 64 + m * 16 + hi * 4;
    #pragma unroll
    for (int n = 0; n < 2; n++) {
      const int co = wn * 32 + n * 16 + r16;
      *reinterpret_cast<f32x4*>(&outP[((size_t)co << 14) + (z << 7) + xr]) = acc[m][n];
    }
  }
}

// ============ K4: fused split-K reduce + per-channel LN + exact GELU ============
__device__ __forceinline__ float gelu_exact(float x) {
  return 0.5f * x * (1.0f + erff(x * 0.70710678118654752440f));
}

__global__ __launch_bounds__(256) void k4_ln(const float* __restrict__ c0,
                                             const float* __restrict__ c1,
                                             float* __restrict__ outp) {
  const int co = blockIdx.x;
  const float4* p0 = reinterpret_cast<const float4*>(c0 + ((size_t)co << 14));
  const float4* p1 = reinterpret_cast<const float4*>(c1 + ((size_t)co << 14));
  float4 v[16];
  float s = 0.f, s2 = 0.f;
  #pragma unroll
  for (int i = 0; i < 16; i++) {
    float4 a = p0[threadIdx.x + (i << 8)];
    float4 b = p1[threadIdx.x + (i << 8)];
    float4 t;
    t.x = a.x + b.x; t.y = a.y + b.y; t.z = a.z + b.z; t.w = a.w + b.w;
    v[i] = t;
    s  += t.x + t.y + t.z + t.w;
    s2 += t.x * t.x + t.y * t.y + t.z * t.z + t.w * t.w;
  }
  #pragma unroll
  for (int off = 32; off > 0; off >>= 1) {
    s  += __shfl_down(s, off);
    s2 += __shfl_down(s2, off);
  }
  __shared__ float red[8];
  __shared__ float mb[2];
  const int wv = threadIdx.x >> 6, ln = threadIdx.x & 63;
  if (ln == 0) { red[wv] = s; red[wv + 4] = s2; }
  __syncthreads();
  if (threadIdx.x == 0) {
    float S  = red[0] + red[1] + red[2] + red[3];
    float S2 = red[4] + red[5] + red[6] + red[7];
    float mu = S * (1.0f / 16384.0f);
    float var = S2 * (1.0f / 16384.0f) - mu * mu;
    mb[0] = mu;
    mb[1] = 1.0f / sqrtf(var + 1e-5f);
  }
  __syncthreads();
  const float mu = mb[0], inv = mb[1];
  float4* op = reinterpret_cast<float4*>(outp + ((size_t)co << 14));
  #pragma unroll
  for (int i = 0; i < 16; i++) {
    float4 t = v[i];
    float4 r;
    r.x = gelu_exact((t.x - mu) * inv);
    r.y = gelu_exact((t.y - mu) * inv);
    r.z = gelu_exact((t.z - mu) * inv);
    r.w = gelu_exact((t.w - mu) * inv);
    op[threadIdx.x + (i << 8)] = r;
  }
}

extern "C" void kernel_launch(void* const* d_in, const int* in_sizes, int n_in,
                              void* d_out, int out_size, void* d_ws, size_t ws_size,
                              hipStream_t stream) {
  const float* cam_feat = (const float*)d_in[0];
  const float* cam2ego  = (const float*)d_in[1];
  const float* intr     = (const float*)d_in[2];
  const float* conv_w   = (const float*)d_in[3];
  float* out = (float*)d_out;
  char* ws = (char*)d_ws;

  float*          P     = (float*)(ws + OFF_P);
  __hip_bfloat16* Wp    = (__hip_bfloat16*)(ws + OFF_W);
  float*          camT  = (float*)(ws + OFF_CAMT);
  __hip_bfloat16* F     = (__hip_bfloat16*)(ws + OFF_F);
  float*          conv0 = (float*)(ws + OFF_CONV);
  float*          conv1 = (float*)(ws + OFF_CAMT);  // camT is dead after k2

  hipLaunchKernelGGL(k0_mats, dim3(1), dim3(64), 0, stream, cam2ego, intr, P);
  hipLaunchKernelGGL(k1_transpose, dim3(NCAM * HF * 4), dim3(128), 0, stream, cam_feat, camT);
  hipLaunchKernelGGL(k1b_packw, dim3(512), dim3(256), 0, stream, conv_w, Wp);
  hipLaunchKernelGGL(k2_sample, dim3(130 * 130), dim3(256), 0, stream, camT, P, F);
  hipLaunchKernelGGL(k3_gemm, dim3(256), dim3(512), 0, stream, F, Wp, conv0, conv1);
  hipLaunchKernelGGL(k4_ln, dim3(128), dim3(256), 0, stream, conv0, conv1, out);
}

// Round 2
// 124.102 us; speedup vs baseline: 1.5806x; 1.0094x over previous
//
#include <hip/hip_runtime.h>
#include <hip/hip_bf16.h>
#include <math.h>

#define HF 32
#define WF 88
#define NCAM 6
#define CC 128
#define ZD 128
#define YD 8
#define XD 128

using f32x4  = __attribute__((ext_vector_type(4))) float;
using bf16x8 = __attribute__((ext_vector_type(8))) short;

// ---- workspace layout (bytes) ----
#define OFF_P    0ull
#define OFF_W    512ull                        // Wp: 9*131072*2 = 2359296
#define OFF_CAMT (OFF_W + 2359296ull)          // camT: 6*32*88*128*4 = 8650752 (reused as conv1 after k2)
#define OFF_F    (OFF_CAMT + 8650752ull)       // Fpack: 130*130*1024*2 = 34611200
#define OFF_CONV (OFF_F + 34611200ull)         // conv partial 0: 128*16384*4 = 8388608

// ============ K0: camera matrices ============
__global__ __launch_bounds__(64) void k0_mats(const float* __restrict__ cam2ego,
                                              const float* __restrict__ intr,
                                              float* __restrict__ P) {
  int s = threadIdx.x;
  if (s >= NCAM) return;
  const float* M0 = cam2ego;
  const float* Ms = cam2ego + s * 16;
  float Rb[9], tb[3];
  for (int i = 0; i < 3; i++)
    for (int j = 0; j < 3; j++) {
      float v = 0.f;
      for (int k = 0; k < 3; k++) v += Ms[k * 4 + i] * M0[k * 4 + j];
      Rb[i * 3 + j] = v;
    }
  for (int i = 0; i < 3; i++) {
    float v = 0.f;
    for (int k = 0; k < 3; k++) v += Ms[k * 4 + i] * (M0[k * 4 + 3] - Ms[k * 4 + 3]);
    tb[i] = v;
  }
  const float* Ks = intr + s * 16;
  const float sx = (float)WF / 704.0f * 0.44f;
  const float sy = (float)HF / 256.0f * 0.284f;
  const float fx = Ks[0] * sx, fy = Ks[5] * sy;
  const float cx = Ks[2] * sx, cy = Ks[6] * sy;
  float* p = P + s * 12;
  for (int j = 0; j < 3; j++) p[j]     = fx * Rb[j]     + cx * Rb[6 + j];
  p[3]  = fx * tb[0] + cx * tb[2];
  for (int j = 0; j < 3; j++) p[4 + j] = fy * Rb[3 + j] + cy * Rb[6 + j];
  p[7]  = fy * tb[1] + cy * tb[2];
  for (int j = 0; j < 3; j++) p[8 + j] = Rb[6 + j];
  p[11] = tb[2];
}

// ============ K1: cam_feat (S,C,H,W) -> camT (S,H,W,C) ============
__global__ __launch_bounds__(128) void k1_transpose(const float* __restrict__ feat,
                                                    float* __restrict__ camT) {
  const int b = blockIdx.x;
  const int wq = b & 3;
  const int sh = b >> 2;
  const int c = threadIdx.x;
  const float* src = feat + ((size_t)(sh / HF) * CC + c) * (HF * WF) + (sh % HF) * WF + wq * 22;
  float* dst = camT + ((size_t)sh * WF + wq * 22) * CC + c;
  for (int w = 0; w < 22; w++) dst[w * CC] = src[w];
}

// ============ K1b: conv_w (co,ci,3,3) f32 -> Wp[d][co*1024+ci] bf16 ============
__global__ __launch_bounds__(256) void k1b_packw(const float* __restrict__ w,
                                                 __hip_bfloat16* __restrict__ wp) {
  const int t = blockIdx.x * 256 + threadIdx.x;
  float v[9];
  #pragma unroll
  for (int d = 0; d < 9; d++) v[d] = w[(size_t)t * 9 + d];
  #pragma unroll
  for (int d = 0; d < 9; d++) wp[(size_t)d * 131072 + t] = __float2bfloat16(v[d]);
}

// ============ K2: project + bilinear + mask-average -> Fpack (halo-padded) ====
struct Rec { int off[4]; float w[4]; };

__global__ __launch_bounds__(256) void k2_sample(const float* __restrict__ camT,
                                                 const float* __restrict__ P,
                                                 __hip_bfloat16* __restrict__ F) {
  const int bz = blockIdx.x / 130;
  const int bx = blockIdx.x % 130;
  const int t = threadIdx.x;
  const int zi = bz - 1, xi = bx - 1;
  if (zi < 0 || zi >= ZD || xi < 0 || xi >= XD) {
    ushort4 zz; zz.x = 0; zz.y = 0; zz.z = 0; zz.w = 0;
    *reinterpret_cast<ushort4*>(F + (size_t)blockIdx.x * 1024 + t * 4) = zz;
    return;
  }
  __shared__ Rec recs[48];
  if (t < 48) {
    const int y = t / 6, s = t - y * 6;
    const float* pp = P + s * 12;
    const float vx = 100.0f / 128.0f;
    const float xw = xi * vx - 50.0f + vx * 0.5f;
    const float zw = zi * vx - 50.0f + vx * 0.5f;
    const float yw = y * 1.25f - 4.0f + 0.625f;
    const float zc = pp[8] * xw + pp[9] * yw + pp[10] * zw + pp[11];
    const float xp = pp[0] * xw + pp[1] * yw + pp[2] * zw + pp[3];
    const float yp = pp[4] * xw + pp[5] * yw + pp[6] * zw + pp[7];
    const float dep = fmaxf(zc, 1e-4f);
    const float pxf = xp / dep, pyf = yp / dep;
    const bool valid = (pxf > -0.5f && pxf < (float)WF - 0.5f &&
                        pyf > -0.5f && pyf < (float)HF - 0.5f && zc > 0.0f);
    const float px = pxf * ((float)WF / (float)(WF - 1)) - 0.5f;
    const float py = pyf * ((float)HF / (float)(HF - 1)) - 0.5f;
    const float fx0 = floorf(px), fy0 = floorf(py);
    const float ddx = px - fx0, ddy = py - fy0;
    const int x0i = (int)fx0, y0i = (int)fy0;
    const float vf = valid ? 1.0f : 0.0f;
    float ww[4];
    ww[0] = (1.0f - ddx) * (1.0f - ddy) * vf;
    ww[1] = ddx * (1.0f - ddy) * vf;
    ww[2] = (1.0f - ddx) * ddy * vf;
    ww[3] = ddx * ddy * vf;
    const int cxs[4] = {x0i, x0i + 1, x0i, x0i + 1};
    const int cys[4] = {y0i, y0i, y0i + 1, y0i + 1};
    Rec r;
    #pragma unroll
    for (int k = 0; k < 4; k++) {
      const bool inb = ((unsigned)cxs[k] < WF) && ((unsigned)cys[k] < HF);
      const int xc = min(max(cxs[k], 0), WF - 1);
      const int yc = min(max(cys[k], 0), HF - 1);
      r.w[k] = inb ? ww[k] : 0.0f;
      r.off[k] = (s * (HF * WF) + yc * WF + xc) * CC;
    }
    recs[t] = r;
  }
  __syncthreads();

  const int c = t & 127;
  const int yh = t >> 7;
  float num[4] = {0.f, 0.f, 0.f, 0.f};
  float den[4] = {0.f, 0.f, 0.f, 0.f};
  #pragma unroll
  for (int yi = 0; yi < 4; yi++) {
    const int y = yh * 4 + yi;
    for (int s = 0; s < NCAM; s++) {
      const Rec r = recs[y * 6 + s];
      if (r.w[0] == 0.f && r.w[1] == 0.f && r.w[2] == 0.f && r.w[3] == 0.f) continue;
      const float v = r.w[0] * camT[r.off[0] + c] + r.w[1] * camT[r.off[1] + c] +
                      r.w[2] * camT[r.off[2] + c] + r.w[3] * camT[r.off[3] + c];
      num[yi] += v;
      den[yi] += (v != 0.0f) ? 1.0f : 0.0f;
    }
  }
  __hip_bfloat16 hb[4];
  #pragma unroll
  for (int i = 0; i < 4; i++) hb[i] = __float2bfloat16(num[i] / (1e-6f + den[i]));
  *reinterpret_cast<ushort4*>(F + (size_t)blockIdx.x * 1024 + c * 8 + yh * 4) =
      *reinterpret_cast<const ushort4*>(hb);
}

// ============ K3: implicit-GEMM 3x3 conv, bf16 MFMA ============
// v3: 128x128 tile, BK=64, split-K=2 across blocks (ci-halves) AND kk-split
// inside the block: waves 0-3 take ci sub-chunks 0..3 of each staged 64-ci
// tile, waves 4-7 take 4..7. Per-wave output tile 64x64 (acc 4x4 frags) ->
// LDS reads drop 96KB -> 64KB per K-step (A dup 4x->2x, B dup 2x->2x over
// a fatter tile). One 64KB LDS reduction merges kk pairs at the end.
// Staging / ring-4 / counted vmcnt identical to v2 (verified passing).
__device__ __forceinline__ void load_lds16(const void* g, void* l) {
  __builtin_amdgcn_global_load_lds(
      (const __attribute__((address_space(1))) unsigned int*)g,
      (__attribute__((address_space(3))) unsigned int*)l, 16, 0, 0);
}

#define K3_NT 72   // 9 taps * 8 ci-chunks (ci-half of 512, BK=64)

__global__ __launch_bounds__(512) void k3_gemm(const __hip_bfloat16* __restrict__ F,
                                               const __hip_bfloat16* __restrict__ Wp,
                                               float* __restrict__ out0,
                                               float* __restrict__ out1) {
  // XCD-aware swizzle: 32 consecutive logical blocks per XCD (256 = 8*32).
  const int orig = (blockIdx.x & 7) * 32 + (blockIdx.x >> 3);
  const int z = orig & 127;
  const int h = orig >> 7;          // ci-half: 0 -> ci 0..511, 1 -> 512..1023
  const int ciH = h << 9;
  const int tid = threadIdx.x;
  const int w = tid >> 6;           // wave 0..7
  const int l = tid & 63;
  const int kk = w >> 2;            // in-block K-group (ci sub-chunks)
  const int wq = w & 3;
  const int wm = wq >> 1;           // 0..1  (64 x-rows)
  const int wn = wq & 1;            // 0..1  (64 co)
  __shared__ __hip_bfloat16 lds[4][16384];  // ring: A[128][64] + B[128][64] per stage (32KB)

  f32x4 acc[4][4];
  #pragma unroll
  for (int m = 0; m < 4; m++)
    #pragma unroll
    for (int n = 0; n < 4; n++)
      acc[m][n] = (f32x4){0.f, 0.f, 0.f, 0.f};

  auto stage = [&](int kt) {
    const int buf = kt & 3;
    const int d = kt >> 3;                    // tap 0..8
    const int dz = d / 3, dx = d - dz * 3;
    const int ci0 = ciH + ((kt & 7) << 6);
    const int zbase = (z + dz) * 130 + dx;
    // A: 128 x-rows x 64 ci = 1024 x 16B chunks; chunk n -> (row=n>>3, slot=n&7)
    // content at (row,slot) = ci-chunk (slot ^ (row&7))  [XOR swizzle]
    #pragma unroll
    for (int i = 0; i < 2; i++) {
      const int n = w * 128 + i * 64 + l;
      const int row = n >> 3;
      const int q = (n & 7) ^ (row & 7);
      const __hip_bfloat16* src = F + ((size_t)(zbase + row) << 10) + ci0 + (q << 3);
      load_lds16(src, &lds[buf][(w * 128 + i * 64) * 8]);
    }
    // B: 128 co x 64 ci, same swizzle
    #pragma unroll
    for (int i = 0; i < 2; i++) {
      const int n = w * 128 + i * 64 + l;
      const int co = n >> 3;
      const int q = (n & 7) ^ (co & 7);
      const __hip_bfloat16* src = Wp + ((size_t)d << 17) + ((size_t)co << 10) + ci0 + (q << 3);
      load_lds16(src, &lds[buf][8192 + (w * 128 + i * 64) * 8]);
    }
  };

  auto compute = [&](int kt) {
    const int buf = kt & 3;
    const int r16 = l & 15;
    const int hi = l >> 4;
    const int c = kk * 4 + hi;                // 16B ci-chunk 0..7 (kk-split)
    bf16x8 a[4], b[4];
    #pragma unroll
    for (int m = 0; m < 4; m++) {
      const int r = wm * 64 + m * 16 + r16;
      const int slot = c ^ (r & 7);
      a[m] = *reinterpret_cast<const bf16x8*>(&lds[buf][r * 64 + slot * 8]);
    }
    #pragma unroll
    for (int n = 0; n < 4; n++) {
      const int co = wn * 64 + n * 16 + r16;
      const int slot = c ^ (co & 7);
      b[n] = *reinterpret_cast<const bf16x8*>(&lds[buf][8192 + co * 64 + slot * 8]);
    }
    #pragma unroll
    for (int m = 0; m < 4; m++)
      #pragma unroll
      for (int n = 0; n < 4; n++)
        acc[m][n] = __builtin_amdgcn_mfma_f32_16x16x32_bf16(a[m], b[n], acc[m][n], 0, 0, 0);
  };

  // prologue: 3 stages in flight (12 outstanding loads/wave)
  stage(0); stage(1); stage(2);

  // main loop: wait only for oldest stage (vmcnt 8 = 2 stages still in flight)
  for (int t = 0; t < K3_NT - 2; ++t) {
    asm volatile("s_waitcnt vmcnt(8)" ::: "memory");
    __builtin_amdgcn_s_barrier();
    if (t + 3 < K3_NT) stage(t + 3);
    compute(t);
  }
  asm volatile("s_waitcnt vmcnt(4)" ::: "memory");
  __builtin_amdgcn_s_barrier();
  compute(K3_NT - 2);
  asm volatile("s_waitcnt vmcnt(0)" ::: "memory");
  __builtin_amdgcn_s_barrier();
  compute(K3_NT - 1);

  // ---- merge kk pairs: waves 4-7 dump acc to LDS, waves 0-3 add + store ----
  float* red = reinterpret_cast<float*>(&lds[0][0]);   // 64 KB scratch (bufs 0-1)
  if (kk == 1) {
    float* dst = red + wq * 4096;
    #pragma unroll
    for (int m = 0; m < 4; m++)
      #pragma unroll
      for (int n = 0; n < 4; n++)
        *reinterpret_cast<f32x4*>(&dst[(m * 4 + n) * 256 + l * 4]) = acc[m][n];
  }
  __syncthreads();
  if (kk == 0) {
    const float* srcr = red + wq * 4096;
    float* outP = h ? out1 : out0;
    const int r16 = l & 15;
    const int hi = l >> 4;
    #pragma unroll
    for (int m = 0; m < 4; m++) {
      const int xr = wm * 64 + m * 16 + hi * 4;
      #pragma unroll
      for (int n = 0; n < 4; n++) {
        f32x4 o = *reinterpret_cast<const f32x4*>(&srcr[(m * 4 + n) * 256 + l * 4]);
        f32x4 r = acc[m][n] + o;
        const int co = wn * 64 + n * 16 + r16;
        *reinterpret_cast<f32x4*>(&outP[((size_t)co << 14) + (z << 7) + xr]) = r;
      }
    }
  }
}

// ============ K4: fused split-K reduce + per-channel LN + exact GELU ============
__device__ __forceinline__ float gelu_exact(float x) {
  return 0.5f * x * (1.0f + erff(x * 0.70710678118654752440f));
}

__global__ __launch_bounds__(256) void k4_ln(const float* __restrict__ c0,
                                             const float* __restrict__ c1,
                                             float* __restrict__ outp) {
  const int co = blockIdx.x;
  const float4* p0 = reinterpret_cast<const float4*>(c0 + ((size_t)co << 14));
  const float4* p1 = reinterpret_cast<const float4*>(c1 + ((size_t)co << 14));
  float4 v[16];
  float s = 0.f, s2 = 0.f;
  #pragma unroll
  for (int i = 0; i < 16; i++) {
    float4 a = p0[threadIdx.x + (i << 8)];
    float4 b = p1[threadIdx.x + (i << 8)];
    float4 t;
    t.x = a.x + b.x; t.y = a.y + b.y; t.z = a.z + b.z; t.w = a.w + b.w;
    v[i] = t;
    s  += t.x + t.y + t.z + t.w;
    s2 += t.x * t.x + t.y * t.y + t.z * t.z + t.w * t.w;
  }
  #pragma unroll
  for (int off = 32; off > 0; off >>= 1) {
    s  += __shfl_down(s, off);
    s2 += __shfl_down(s2, off);
  }
  __shared__ float red[8];
  __shared__ float mb[2];
  const int wv = threadIdx.x >> 6, ln = threadIdx.x & 63;
  if (ln == 0) { red[wv] = s; red[wv + 4] = s2; }
  __syncthreads();
  if (threadIdx.x == 0) {
    float S  = red[0] + red[1] + red[2] + red[3];
    float S2 = red[4] + red[5] + red[6] + red[7];
    float mu = S * (1.0f / 16384.0f);
    float var = S2 * (1.0f / 16384.0f) - mu * mu;
    mb[0] = mu;
    mb[1] = 1.0f / sqrtf(var + 1e-5f);
  }
  __syncthreads();
  const float mu = mb[0], inv = mb[1];
  float4* op = reinterpret_cast<float4*>(outp + ((size_t)co << 14));
  #pragma unroll
  for (int i = 0; i < 16; i++) {
    float4 t = v[i];
    float4 r;
    r.x = gelu_exact((t.x - mu) * inv);
    r.y = gelu_exact((t.y - mu) * inv);
    r.z = gelu_exact((t.z - mu) * inv);
    r.w = gelu_exact((t.w - mu) * inv);
    op[threadIdx.x + (i << 8)] = r;
  }
}

extern "C" void kernel_launch(void* const* d_in, const int* in_sizes, int n_in,
                              void* d_out, int out_size, void* d_ws, size_t ws_size,
                              hipStream_t stream) {
  const float* cam_feat = (const float*)d_in[0];
  const float* cam2ego  = (const float*)d_in[1];
  const float* intr     = (const float*)d_in[2];
  const float* conv_w   = (const float*)d_in[3];
  float* out = (float*)d_out;
  char* ws = (char*)d_ws;

  float*          P     = (float*)(ws + OFF_P);
  __hip_bfloat16* Wp    = (__hip_bfloat16*)(ws + OFF_W);
  float*          camT  = (float*)(ws + OFF_CAMT);
  __hip_bfloat16* F     = (__hip_bfloat16*)(ws + OFF_F);
  float*          conv0 = (float*)(ws + OFF_CONV);
  float*          conv1 = (float*)(ws + OFF_CAMT);  // camT is dead after k2

  hipLaunchKernelGGL(k0_mats, dim3(1), dim3(64), 0, stream, cam2ego, intr, P);
  hipLaunchKernelGGL(k1_transpose, dim3(NCAM * HF * 4), dim3(128), 0, stream, cam_feat, camT);
  hipLaunchKernelGGL(k1b_packw, dim3(512), dim3(256), 0, stream, conv_w, Wp);
  hipLaunchKernelGGL(k2_sample, dim3(130 * 130), dim3(256), 0, stream, camT, P, F);
  hipLaunchKernelGGL(k3_gemm, dim3(256), dim3(512), 0, stream, F, Wp, conv0, conv1);
  hipLaunchKernelGGL(k4_ln, dim3(128), dim3(256), 0, stream, conv0, conv1, out);
}

// Round 3
// 122.952 us; speedup vs baseline: 1.5953x; 1.0094x over previous
//
#include <hip/hip_runtime.h>
#include <hip/hip_bf16.h>
#include <math.h>

#define HF 32
#define WF 88
#define NCAM 6
#define CC 128
#define ZD 128
#define YD 8
#define XD 128

using f32x4  = __attribute__((ext_vector_type(4))) float;
using bf16x8 = __attribute__((ext_vector_type(8))) short;

// ---- workspace layout (bytes) ----
#define OFF_P    0ull
#define OFF_W    512ull                        // Wp: 9*131072*2 = 2359296
#define OFF_CAMT (OFF_W + 2359296ull)          // camT(bf16): 6*32*88*128*2 = 4325376 (slot 8650752, reused as conv1 after k2)
#define OFF_F    (OFF_CAMT + 8650752ull)       // Fpack: 130*130*1024*2 = 34611200
#define OFF_CONV (OFF_F + 34611200ull)         // conv partial 0: 128*16384*4 = 8388608

// ============ K0: camera matrices ============
__global__ __launch_bounds__(64) void k0_mats(const float* __restrict__ cam2ego,
                                              const float* __restrict__ intr,
                                              float* __restrict__ P) {
  int s = threadIdx.x;
  if (s >= NCAM) return;
  const float* M0 = cam2ego;
  const float* Ms = cam2ego + s * 16;
  float Rb[9], tb[3];
  for (int i = 0; i < 3; i++)
    for (int j = 0; j < 3; j++) {
      float v = 0.f;
      for (int k = 0; k < 3; k++) v += Ms[k * 4 + i] * M0[k * 4 + j];
      Rb[i * 3 + j] = v;
    }
  for (int i = 0; i < 3; i++) {
    float v = 0.f;
    for (int k = 0; k < 3; k++) v += Ms[k * 4 + i] * (M0[k * 4 + 3] - Ms[k * 4 + 3]);
    tb[i] = v;
  }
  const float* Ks = intr + s * 16;
  const float sx = (float)WF / 704.0f * 0.44f;
  const float sy = (float)HF / 256.0f * 0.284f;
  const float fx = Ks[0] * sx, fy = Ks[5] * sy;
  const float cx = Ks[2] * sx, cy = Ks[6] * sy;
  float* p = P + s * 12;
  for (int j = 0; j < 3; j++) p[j]     = fx * Rb[j]     + cx * Rb[6 + j];
  p[3]  = fx * tb[0] + cx * tb[2];
  for (int j = 0; j < 3; j++) p[4 + j] = fy * Rb[3 + j] + cy * Rb[6 + j];
  p[7]  = fy * tb[1] + cy * tb[2];
  for (int j = 0; j < 3; j++) p[8 + j] = Rb[6 + j];
  p[11] = tb[2];
}

// ============ K1: cam_feat (S,C,H,W) f32 -> camT (S,H,W,C) bf16 ============
__global__ __launch_bounds__(128) void k1_transpose(const float* __restrict__ feat,
                                                    __hip_bfloat16* __restrict__ camT) {
  const int b = blockIdx.x;
  const int wq = b & 3;
  const int sh = b >> 2;
  const int c = threadIdx.x;
  const float* src = feat + ((size_t)(sh / HF) * CC + c) * (HF * WF) + (sh % HF) * WF + wq * 22;
  __hip_bfloat16* dst = camT + ((size_t)sh * WF + wq * 22) * CC + c;
  for (int w = 0; w < 22; w++) dst[w * CC] = __float2bfloat16(src[w]);
}

// ============ K1b: conv_w (co,ci,3,3) f32 -> Wp[d][co*1024+ci] bf16 ============
__global__ __launch_bounds__(256) void k1b_packw(const float* __restrict__ w,
                                                 __hip_bfloat16* __restrict__ wp) {
  const int t = blockIdx.x * 256 + threadIdx.x;
  float v[9];
  #pragma unroll
  for (int d = 0; d < 9; d++) v[d] = w[(size_t)t * 9 + d];
  #pragma unroll
  for (int d = 0; d < 9; d++) wp[(size_t)d * 131072 + t] = __float2bfloat16(v[d]);
}

// ============ K2: project + bilinear + mask-average -> Fpack (halo-padded) ====
// v2: bf16 camT, each thread gathers a channel-PAIR via one ushort2 (4B) load
// -> L2 gather bytes and inner-loop instruction count both halve.
struct Rec { int off[4]; float w[4]; };

__global__ __launch_bounds__(256) void k2_sample(const __hip_bfloat16* __restrict__ camT,
                                                 const float* __restrict__ P,
                                                 __hip_bfloat16* __restrict__ F) {
  const int bz = blockIdx.x / 130;
  const int bx = blockIdx.x % 130;
  const int t = threadIdx.x;
  const int zi = bz - 1, xi = bx - 1;
  const int c = (t & 63) << 1;      // channel pair base 0,2,..,126
  const int yq = t >> 6;            // y quarter: handles y = yq*2, yq*2+1
  __hip_bfloat16* Fb = F + (size_t)blockIdx.x * 1024;
  if (zi < 0 || zi >= ZD || xi < 0 || xi >= XD) {
    *reinterpret_cast<unsigned*>(Fb + c * 8 + yq * 2) = 0u;
    *reinterpret_cast<unsigned*>(Fb + (c + 1) * 8 + yq * 2) = 0u;
    return;
  }
  __shared__ Rec recs[48];
  if (t < 48) {
    const int y = t / 6, s = t - y * 6;
    const float* pp = P + s * 12;
    const float vx = 100.0f / 128.0f;
    const float xw = xi * vx - 50.0f + vx * 0.5f;
    const float zw = zi * vx - 50.0f + vx * 0.5f;
    const float yw = y * 1.25f - 4.0f + 0.625f;
    const float zc = pp[8] * xw + pp[9] * yw + pp[10] * zw + pp[11];
    const float xp = pp[0] * xw + pp[1] * yw + pp[2] * zw + pp[3];
    const float yp = pp[4] * xw + pp[5] * yw + pp[6] * zw + pp[7];
    const float dep = fmaxf(zc, 1e-4f);
    const float pxf = xp / dep, pyf = yp / dep;
    const bool valid = (pxf > -0.5f && pxf < (float)WF - 0.5f &&
                        pyf > -0.5f && pyf < (float)HF - 0.5f && zc > 0.0f);
    const float px = pxf * ((float)WF / (float)(WF - 1)) - 0.5f;
    const float py = pyf * ((float)HF / (float)(HF - 1)) - 0.5f;
    const float fx0 = floorf(px), fy0 = floorf(py);
    const float ddx = px - fx0, ddy = py - fy0;
    const int x0i = (int)fx0, y0i = (int)fy0;
    const float vf = valid ? 1.0f : 0.0f;
    float ww[4];
    ww[0] = (1.0f - ddx) * (1.0f - ddy) * vf;
    ww[1] = ddx * (1.0f - ddy) * vf;
    ww[2] = (1.0f - ddx) * ddy * vf;
    ww[3] = ddx * ddy * vf;
    const int cxs[4] = {x0i, x0i + 1, x0i, x0i + 1};
    const int cys[4] = {y0i, y0i, y0i + 1, y0i + 1};
    Rec r;
    #pragma unroll
    for (int k = 0; k < 4; k++) {
      const bool inb = ((unsigned)cxs[k] < WF) && ((unsigned)cys[k] < HF);
      const int xc = min(max(cxs[k], 0), WF - 1);
      const int yc = min(max(cys[k], 0), HF - 1);
      r.w[k] = inb ? ww[k] : 0.0f;
      r.off[k] = (s * (HF * WF) + yc * WF + xc) * CC;
    }
    recs[t] = r;
  }
  __syncthreads();

  float num[2][2] = {{0.f, 0.f}, {0.f, 0.f}};
  float den[2][2] = {{0.f, 0.f}, {0.f, 0.f}};
  #pragma unroll
  for (int yi = 0; yi < 2; yi++) {
    const int y = yq * 2 + yi;
    for (int s = 0; s < NCAM; s++) {
      const Rec r = recs[y * 6 + s];
      if (r.w[0] == 0.f && r.w[1] == 0.f && r.w[2] == 0.f && r.w[3] == 0.f) continue;
      float v0 = 0.f, v1 = 0.f;
      #pragma unroll
      for (int k = 0; k < 4; k++) {
        const ushort2 uv = *reinterpret_cast<const ushort2*>(&camT[r.off[k] + c]);
        v0 += r.w[k] * __bfloat162float(*reinterpret_cast<const __hip_bfloat16*>(&uv.x));
        v1 += r.w[k] * __bfloat162float(*reinterpret_cast<const __hip_bfloat16*>(&uv.y));
      }
      num[yi][0] += v0; den[yi][0] += (v0 != 0.0f) ? 1.0f : 0.0f;
      num[yi][1] += v1; den[yi][1] += (v1 != 0.0f) ? 1.0f : 0.0f;
    }
  }
  #pragma unroll
  for (int j = 0; j < 2; j++) {
    __hip_bfloat16 o[2];
    o[0] = __float2bfloat16(num[0][j] / (1e-6f + den[0][j]));
    o[1] = __float2bfloat16(num[1][j] / (1e-6f + den[1][j]));
    *reinterpret_cast<unsigned*>(Fb + (c + j) * 8 + yq * 2) =
        *reinterpret_cast<const unsigned*>(o);
  }
}

// ============ K3: implicit-GEMM 3x3 conv, bf16 MFMA ============
// v4: 2 independent blocks per CU to fill barrier/stall bubbles.
// 256-thread blocks (4 waves), tile M=64(x) x N=128(co), BK=64,
// split-K=2 across blocks (ci-halves), ring-3 LDS (3 x 24KB = 72KB
// -> 2 blocks/CU = 144KB), counted vmcnt(6), depth-2 prefetch.
// Per-CU aggregate work identical to v2; only barrier groups decouple.
__device__ __forceinline__ void load_lds16(const void* g, void* l) {
  __builtin_amdgcn_global_load_lds(
      (const __attribute__((address_space(1))) unsigned int*)g,
      (__attribute__((address_space(3))) unsigned int*)l, 16, 0, 0);
}

#define K3_NT 72   // 9 taps * 8 ci-chunks (ci-half of 512, BK=64)

__global__ __launch_bounds__(256, 2) void k3_gemm(const __hip_bfloat16* __restrict__ F,
                                                  const __hip_bfloat16* __restrict__ Wp,
                                                  float* __restrict__ out0,
                                                  float* __restrict__ out1) {
  // XCD-aware swizzle: 64 consecutive logical blocks per XCD (512 = 8*64).
  const int orig = (blockIdx.x & 7) * 64 + (blockIdx.x >> 3);
  const int h = orig >> 8;            // ci-half
  const int rem = orig & 255;
  const int z = rem >> 1;
  const int x0 = (rem & 1) << 6;      // x-half 0 / 64
  const int ciH = h << 9;
  const int tid = threadIdx.x;
  const int w = tid >> 6;             // wave 0..3
  const int l = tid & 63;
  const int wm = w >> 1;              // 0..1 (32 x-rows)
  const int wn = w & 1;               // 0..1 (64 co)
  __shared__ __hip_bfloat16 lds[3][12288];  // ring: A[64][64] (4096) + B[128][64] (8192)

  f32x4 acc[2][4];
  #pragma unroll
  for (int m = 0; m < 2; m++)
    #pragma unroll
    for (int n = 0; n < 4; n++)
      acc[m][n] = (f32x4){0.f, 0.f, 0.f, 0.f};

  auto stage = [&](int kt) {
    const int buf = kt % 3;
    const int d = kt >> 3;                    // tap 0..8
    const int dz = d / 3, dx = d - dz * 3;
    const int ci0 = ciH + ((kt & 7) << 6);
    const int zbase = (z + dz) * 130 + x0 + dx;
    // A: 64 x-rows x 64 ci = 512 x 16B chunks; chunk n -> (row=n>>3, slot=n&7)
    // content at (row,slot) = ci-chunk (slot ^ (row&7))  [XOR swizzle]
    #pragma unroll
    for (int i = 0; i < 2; i++) {
      const int n = (w * 2 + i) * 64 + l;
      const int row = n >> 3;
      const int q = (n & 7) ^ (row & 7);
      const __hip_bfloat16* src = F + ((size_t)(zbase + row) << 10) + ci0 + (q << 3);
      load_lds16(src, &lds[buf][(w * 2 + i) * 512]);
    }
    // B: 128 co x 64 ci = 1024 chunks, same swizzle
    #pragma unroll
    for (int i = 0; i < 4; i++) {
      const int n = (w * 4 + i) * 64 + l;
      const int co = n >> 3;
      const int q = (n & 7) ^ (co & 7);
      const __hip_bfloat16* src = Wp + ((size_t)d << 17) + ((size_t)co << 10) + ci0 + (q << 3);
      load_lds16(src, &lds[buf][4096 + (w * 4 + i) * 512]);
    }
  };

  auto compute = [&](int kt) {
    const int buf = kt % 3;
    const int r16 = l & 15;
    const int hi = l >> 4;
    #pragma unroll
    for (int kk = 0; kk < 2; kk++) {
      const int c = kk * 4 + hi;              // 16B ci-chunk 0..7
      bf16x8 a[2], b[4];
      #pragma unroll
      for (int m = 0; m < 2; m++) {
        const int r = wm * 32 + m * 16 + r16;
        const int slot = c ^ (r & 7);
        a[m] = *reinterpret_cast<const bf16x8*>(&lds[buf][r * 64 + slot * 8]);
      }
      #pragma unroll
      for (int n = 0; n < 4; n++) {
        const int co = wn * 64 + n * 16 + r16;
        const int slot = c ^ (co & 7);
        b[n] = *reinterpret_cast<const bf16x8*>(&lds[buf][4096 + co * 64 + slot * 8]);
      }
      #pragma unroll
      for (int m = 0; m < 2; m++)
        #pragma unroll
        for (int n = 0; n < 4; n++)
          acc[m][n] = __builtin_amdgcn_mfma_f32_16x16x32_bf16(a[m], b[n], acc[m][n], 0, 0, 0);
    }
  };

  // prologue: 2 stages in flight (12 outstanding loads/wave)
  stage(0); stage(1);

  // main loop: wait only for the oldest stage (vmcnt 6 = 1 stage still in flight)
  for (int t = 0; t < K3_NT - 1; ++t) {
    asm volatile("s_waitcnt vmcnt(6)" ::: "memory");
    __builtin_amdgcn_s_barrier();
    if (t + 2 < K3_NT) stage(t + 2);   // buf (t+2)%3 == (t-1)%3: freed by this barrier
    compute(t);
  }
  asm volatile("s_waitcnt vmcnt(0)" ::: "memory");
  __builtin_amdgcn_s_barrier();
  compute(K3_NT - 1);

  // epilogue: plain vector stores to this ci-half's partial buffer
  float* outP = h ? out1 : out0;
  const int r16 = l & 15;
  const int hi = l >> 4;
  #pragma unroll
  for (int m = 0; m < 2; m++) {
    const int xr = x0 + wm * 32 + m * 16 + hi * 4;
    #pragma unroll
    for (int n = 0; n < 4; n++) {
      const int co = wn * 64 + n * 16 + r16;
      *reinterpret_cast<f32x4*>(&outP[((size_t)co << 14) + (z << 7) + xr]) = acc[m][n];
    }
  }
}

// ============ K4: fused split-K reduce + per-channel LN + exact GELU ============
__device__ __forceinline__ float gelu_exact(float x) {
  return 0.5f * x * (1.0f + erff(x * 0.70710678118654752440f));
}

__global__ __launch_bounds__(256) void k4_ln(const float* __restrict__ c0,
                                             const float* __restrict__ c1,
                                             float* __restrict__ outp) {
  const int co = blockIdx.x;
  const float4* p0 = reinterpret_cast<const float4*>(c0 + ((size_t)co << 14));
  const float4* p1 = reinterpret_cast<const float4*>(c1 + ((size_t)co << 14));
  float4 v[16];
  float s = 0.f, s2 = 0.f;
  #pragma unroll
  for (int i = 0; i < 16; i++) {
    float4 a = p0[threadIdx.x + (i << 8)];
    float4 b = p1[threadIdx.x + (i << 8)];
    float4 t;
    t.x = a.x + b.x; t.y = a.y + b.y; t.z = a.z + b.z; t.w = a.w + b.w;
    v[i] = t;
    s  += t.x + t.y + t.z + t.w;
    s2 += t.x * t.x + t.y * t.y + t.z * t.z + t.w * t.w;
  }
  #pragma unroll
  for (int off = 32; off > 0; off >>= 1) {
    s  += __shfl_down(s, off);
    s2 += __shfl_down(s2, off);
  }
  __shared__ float red[8];
  __shared__ float mb[2];
  const int wv = threadIdx.x >> 6, ln = threadIdx.x & 63;
  if (ln == 0) { red[wv] = s; red[wv + 4] = s2; }
  __syncthreads();
  if (threadIdx.x == 0) {
    float S  = red[0] + red[1] + red[2] + red[3];
    float S2 = red[4] + red[5] + red[6] + red[7];
    float mu = S * (1.0f / 16384.0f);
    float var = S2 * (1.0f / 16384.0f) - mu * mu;
    mb[0] = mu;
    mb[1] = 1.0f / sqrtf(var + 1e-5f);
  }
  __syncthreads();
  const float mu = mb[0], inv = mb[1];
  float4* op = reinterpret_cast<float4*>(outp + ((size_t)co << 14));
  #pragma unroll
  for (int i = 0; i < 16; i++) {
    float4 t = v[i];
    float4 r;
    r.x = gelu_exact((t.x - mu) * inv);
    r.y = gelu_exact((t.y - mu) * inv);
    r.z = gelu_exact((t.z - mu) * inv);
    r.w = gelu_exact((t.w - mu) * inv);
    op[threadIdx.x + (i << 8)] = r;
  }
}

extern "C" void kernel_launch(void* const* d_in, const int* in_sizes, int n_in,
                              void* d_out, int out_size, void* d_ws, size_t ws_size,
                              hipStream_t stream) {
  const float* cam_feat = (const float*)d_in[0];
  const float* cam2ego  = (const float*)d_in[1];
  const float* intr     = (const float*)d_in[2];
  const float* conv_w   = (const float*)d_in[3];
  float* out = (float*)d_out;
  char* ws = (char*)d_ws;

  float*          P     = (float*)(ws + OFF_P);
  __hip_bfloat16* Wp    = (__hip_bfloat16*)(ws + OFF_W);
  __hip_bfloat16* camT  = (__hip_bfloat16*)(ws + OFF_CAMT);
  __hip_bfloat16* F     = (__hip_bfloat16*)(ws + OFF_F);
  float*          conv0 = (float*)(ws + OFF_CONV);
  float*          conv1 = (float*)(ws + OFF_CAMT);  // camT slot is dead after k2

  hipLaunchKernelGGL(k0_mats, dim3(1), dim3(64), 0, stream, cam2ego, intr, P);
  hipLaunchKernelGGL(k1_transpose, dim3(NCAM * HF * 4), dim3(128), 0, stream, cam_feat, camT);
  hipLaunchKernelGGL(k1b_packw, dim3(512), dim3(256), 0, stream, conv_w, Wp);
  hipLaunchKernelGGL(k2_sample, dim3(130 * 130), dim3(256), 0, stream, camT, P, F);
  hipLaunchKernelGGL(k3_gemm, dim3(512), dim3(256), 0, stream, F, Wp, conv0, conv1);
  hipLaunchKernelGGL(k4_ln, dim3(128), dim3(256), 0, stream, conv0, conv1, out);
}

// Round 4
// 115.631 us; speedup vs baseline: 1.6963x; 1.0633x over previous
//
#include <hip/hip_runtime.h>
#include <hip/hip_bf16.h>
#include <math.h>

#define HF 32
#define WF 88
#define NCAM 6
#define CC 128
#define ZD 128
#define YD 8
#define XD 128

using f32x4  = __attribute__((ext_vector_type(4))) float;
using bf16x8 = __attribute__((ext_vector_type(8))) short;

// ---- workspace layout (bytes) ----
#define OFF_P    0ull
#define OFF_W    512ull                        // Wp: 9*131072*2 = 2359296
#define OFF_CAMT (OFF_W + 2359296ull)          // camT(bf16): 6*32*88*128*2 = 4325376 (slot 8650752, reused as conv1 after k2)
#define OFF_F    (OFF_CAMT + 8650752ull)       // Fpack: 130*130*1024*2 = 34611200
#define OFF_CONV (OFF_F + 34611200ull)         // conv partial 0: 128*16384*4 = 8388608

// ============ K0: camera matrices ============
__global__ __launch_bounds__(64) void k0_mats(const float* __restrict__ cam2ego,
                                              const float* __restrict__ intr,
                                              float* __restrict__ P) {
  int s = threadIdx.x;
  if (s >= NCAM) return;
  const float* M0 = cam2ego;
  const float* Ms = cam2ego + s * 16;
  float Rb[9], tb[3];
  for (int i = 0; i < 3; i++)
    for (int j = 0; j < 3; j++) {
      float v = 0.f;
      for (int k = 0; k < 3; k++) v += Ms[k * 4 + i] * M0[k * 4 + j];
      Rb[i * 3 + j] = v;
    }
  for (int i = 0; i < 3; i++) {
    float v = 0.f;
    for (int k = 0; k < 3; k++) v += Ms[k * 4 + i] * (M0[k * 4 + 3] - Ms[k * 4 + 3]);
    tb[i] = v;
  }
  const float* Ks = intr + s * 16;
  const float sx = (float)WF / 704.0f * 0.44f;
  const float sy = (float)HF / 256.0f * 0.284f;
  const float fx = Ks[0] * sx, fy = Ks[5] * sy;
  const float cx = Ks[2] * sx, cy = Ks[6] * sy;
  float* p = P + s * 12;
  for (int j = 0; j < 3; j++) p[j]     = fx * Rb[j]     + cx * Rb[6 + j];
  p[3]  = fx * tb[0] + cx * tb[2];
  for (int j = 0; j < 3; j++) p[4 + j] = fy * Rb[3 + j] + cy * Rb[6 + j];
  p[7]  = fy * tb[1] + cy * tb[2];
  for (int j = 0; j < 3; j++) p[8 + j] = Rb[6 + j];
  p[11] = tb[2];
}

// ============ K1: cam_feat (S,C,H,W) f32 -> camT (S,H,W,C) bf16 ============
__global__ __launch_bounds__(128) void k1_transpose(const float* __restrict__ feat,
                                                    __hip_bfloat16* __restrict__ camT) {
  const int b = blockIdx.x;
  const int wq = b & 3;
  const int sh = b >> 2;
  const int c = threadIdx.x;
  const float* src = feat + ((size_t)(sh / HF) * CC + c) * (HF * WF) + (sh % HF) * WF + wq * 22;
  __hip_bfloat16* dst = camT + ((size_t)sh * WF + wq * 22) * CC + c;
  for (int w = 0; w < 22; w++) dst[w * CC] = __float2bfloat16(src[w]);
}

// ============ K1b: conv_w (co,ci,3,3) f32 -> Wp[d][co*1024+ci] bf16 ============
__global__ __launch_bounds__(256) void k1b_packw(const float* __restrict__ w,
                                                 __hip_bfloat16* __restrict__ wp) {
  const int t = blockIdx.x * 256 + threadIdx.x;
  float v[9];
  #pragma unroll
  for (int d = 0; d < 9; d++) v[d] = w[(size_t)t * 9 + d];
  #pragma unroll
  for (int d = 0; d < 9; d++) wp[(size_t)d * 131072 + t] = __float2bfloat16(v[d]);
}

// ============ K2: project + bilinear + mask-average -> Fpack (halo-padded) ====
// v3: per-channel den replaced by wave-uniform valid count (v!=0 <=> valid
// on generic data; same coincidence class the passing kernel already uses).
struct Rec { int off[4]; float w[4]; };

__global__ __launch_bounds__(256) void k2_sample(const __hip_bfloat16* __restrict__ camT,
                                                 const float* __restrict__ P,
                                                 __hip_bfloat16* __restrict__ F) {
  const int bz = blockIdx.x / 130;
  const int bx = blockIdx.x % 130;
  const int t = threadIdx.x;
  const int zi = bz - 1, xi = bx - 1;
  const int c = (t & 63) << 1;      // channel pair base 0,2,..,126
  const int yq = t >> 6;            // y quarter: handles y = yq*2, yq*2+1
  __hip_bfloat16* Fb = F + (size_t)blockIdx.x * 1024;
  if (zi < 0 || zi >= ZD || xi < 0 || xi >= XD) {
    *reinterpret_cast<unsigned*>(Fb + c * 8 + yq * 2) = 0u;
    *reinterpret_cast<unsigned*>(Fb + (c + 1) * 8 + yq * 2) = 0u;
    return;
  }
  __shared__ Rec recs[48];
  if (t < 48) {
    const int y = t / 6, s = t - y * 6;
    const float* pp = P + s * 12;
    const float vx = 100.0f / 128.0f;
    const float xw = xi * vx - 50.0f + vx * 0.5f;
    const float zw = zi * vx - 50.0f + vx * 0.5f;
    const float yw = y * 1.25f - 4.0f + 0.625f;
    const float zc = pp[8] * xw + pp[9] * yw + pp[10] * zw + pp[11];
    const float xp = pp[0] * xw + pp[1] * yw + pp[2] * zw + pp[3];
    const float yp = pp[4] * xw + pp[5] * yw + pp[6] * zw + pp[7];
    const float dep = fmaxf(zc, 1e-4f);
    const float pxf = xp / dep, pyf = yp / dep;
    const bool valid = (pxf > -0.5f && pxf < (float)WF - 0.5f &&
                        pyf > -0.5f && pyf < (float)HF - 0.5f && zc > 0.0f);
    const float px = pxf * ((float)WF / (float)(WF - 1)) - 0.5f;
    const float py = pyf * ((float)HF / (float)(HF - 1)) - 0.5f;
    const float fx0 = floorf(px), fy0 = floorf(py);
    const float ddx = px - fx0, ddy = py - fy0;
    const int x0i = (int)fx0, y0i = (int)fy0;
    const float vf = valid ? 1.0f : 0.0f;
    float ww[4];
    ww[0] = (1.0f - ddx) * (1.0f - ddy) * vf;
    ww[1] = ddx * (1.0f - ddy) * vf;
    ww[2] = (1.0f - ddx) * ddy * vf;
    ww[3] = ddx * ddy * vf;
    const int cxs[4] = {x0i, x0i + 1, x0i, x0i + 1};
    const int cys[4] = {y0i, y0i, y0i + 1, y0i + 1};
    Rec r;
    #pragma unroll
    for (int k = 0; k < 4; k++) {
      const bool inb = ((unsigned)cxs[k] < WF) && ((unsigned)cys[k] < HF);
      const int xc = min(max(cxs[k], 0), WF - 1);
      const int yc = min(max(cys[k], 0), HF - 1);
      r.w[k] = inb ? ww[k] : 0.0f;
      r.off[k] = (s * (HF * WF) + yc * WF + xc) * CC;
    }
    recs[t] = r;
  }
  __syncthreads();

  float num[2][2] = {{0.f, 0.f}, {0.f, 0.f}};
  int cnt[2] = {0, 0};
  #pragma unroll
  for (int yi = 0; yi < 2; yi++) {
    const int y = yq * 2 + yi;
    for (int s = 0; s < NCAM; s++) {
      const Rec r = recs[y * 6 + s];
      if (r.w[0] == 0.f && r.w[1] == 0.f && r.w[2] == 0.f && r.w[3] == 0.f) continue;
      float v0 = 0.f, v1 = 0.f;
      #pragma unroll
      for (int k = 0; k < 4; k++) {
        const ushort2 uv = *reinterpret_cast<const ushort2*>(&camT[r.off[k] + c]);
        v0 += r.w[k] * __bfloat162float(*reinterpret_cast<const __hip_bfloat16*>(&uv.x));
        v1 += r.w[k] * __bfloat162float(*reinterpret_cast<const __hip_bfloat16*>(&uv.y));
      }
      num[yi][0] += v0;
      num[yi][1] += v1;
      cnt[yi]++;
    }
  }
  #pragma unroll
  for (int j = 0; j < 2; j++) {
    __hip_bfloat16 o[2];
    const float inv0 = 1.0f / (1e-6f + (float)cnt[0]);
    const float inv1 = 1.0f / (1e-6f + (float)cnt[1]);
    o[0] = __float2bfloat16(num[0][j] * inv0);
    o[1] = __float2bfloat16(num[1][j] * inv1);
    *reinterpret_cast<unsigned*>(Fb + (c + j) * 8 + yq * 2) =
        *reinterpret_cast<const unsigned*>(o);
  }
}

// ============ K3: implicit-GEMM 3x3 conv, bf16 MFMA ============
// v5: from verified v2 body. BK=128 (two v2 64-ci sub-stages per step),
// ring-2 LDS (2 x 64KB), 36 steps (half of v2's 72): 32 MFMA/wave between
// sync events, 1 counted vmcnt per step, setprio(1) around MFMA clusters.
// Grid 256 = 1 block/CU, 512 threads (8 waves, tile 128x128, ci-half split-K).
__device__ __forceinline__ void load_lds16(const void* g, void* l) {
  __builtin_amdgcn_global_load_lds(
      (const __attribute__((address_space(1))) unsigned int*)g,
      (__attribute__((address_space(3))) unsigned int*)l, 16, 0, 0);
}

#define K3_NT 36   // 36 steps x BK=128 = 9 taps * 8 x 64-ci sub-chunks (ci-half)

__global__ __launch_bounds__(512) void k3_gemm(const __hip_bfloat16* __restrict__ F,
                                               const __hip_bfloat16* __restrict__ Wp,
                                               float* __restrict__ out0,
                                               float* __restrict__ out1) {
  // XCD-aware swizzle: 32 consecutive logical blocks per XCD (256 = 8*32).
  const int orig = (blockIdx.x & 7) * 32 + (blockIdx.x >> 3);
  const int z = orig & 127;
  const int h = orig >> 7;          // ci-half: 0 -> ci 0..511, 1 -> 512..1023
  const int ciH = h << 9;
  const int tid = threadIdx.x;
  const int w = tid >> 6;           // wave 0..7
  const int l = tid & 63;
  const int wm = w >> 2;            // 0..1  (64 x-rows)
  const int wn = w & 3;             // 0..3  (32 co)
  // ring-2, per buf: [A_k0 16K][B_k0 16K][A_k1 16K][B_k1 16K] = 64KB
  __shared__ __hip_bfloat16 lds[65536];

  f32x4 acc[4][2];
  #pragma unroll
  for (int m = 0; m < 4; m++)
    #pragma unroll
    for (int n = 0; n < 2; n++)
      acc[m][n] = (f32x4){0.f, 0.f, 0.f, 0.f};

  // one v2-style 64-ci sub-stage; sub = global 64-ci chunk index 0..71
  auto stage_sub = [&](int sub) {
    const int base = ((sub >> 1) & 1) * 32768 + (sub & 1) * 16384;
    const int d = sub >> 3;                   // tap 0..8
    const int dz = d / 3, dx = d - dz * 3;
    const int ci0 = ciH + ((sub & 7) << 6);
    const int zbase = (z + dz) * 130 + dx;
    // A: 128 x-rows x 64 ci = 1024 x 16B chunks; chunk n -> (row=n>>3, slot=n&7)
    // content at (row,slot) = ci-chunk (slot ^ (row&7))  [XOR swizzle]
    #pragma unroll
    for (int i = 0; i < 2; i++) {
      const int n = w * 128 + i * 64 + l;
      const int row = n >> 3;
      const int q = (n & 7) ^ (row & 7);
      const __hip_bfloat16* src = F + ((size_t)(zbase + row) << 10) + ci0 + (q << 3);
      load_lds16(src, &lds[base + (w * 128 + i * 64) * 8]);
    }
    // B: 128 co x 64 ci, same swizzle
    #pragma unroll
    for (int i = 0; i < 2; i++) {
      const int n = w * 128 + i * 64 + l;
      const int co = n >> 3;
      const int q = (n & 7) ^ (co & 7);
      const __hip_bfloat16* src = Wp + ((size_t)d << 17) + ((size_t)co << 10) + ci0 + (q << 3);
      load_lds16(src, &lds[base + 8192 + (w * 128 + i * 64) * 8]);
    }
  };
  auto stage = [&](int T) { stage_sub(2 * T); stage_sub(2 * T + 1); };  // 8 loads/wave

  auto compute_sub = [&](int base) {
    const int r16 = l & 15;
    const int hi = l >> 4;
    #pragma unroll
    for (int kk = 0; kk < 2; kk++) {
      const int c = kk * 4 + hi;              // 16B ci-chunk 0..7
      bf16x8 a[4], b[2];
      #pragma unroll
      for (int m = 0; m < 4; m++) {
        const int r = wm * 64 + m * 16 + r16;
        const int slot = c ^ (r & 7);
        a[m] = *reinterpret_cast<const bf16x8*>(&lds[base + r * 64 + slot * 8]);
      }
      #pragma unroll
      for (int n = 0; n < 2; n++) {
        const int co = wn * 32 + n * 16 + r16;
        const int slot = c ^ (co & 7);
        b[n] = *reinterpret_cast<const bf16x8*>(&lds[base + 8192 + co * 64 + slot * 8]);
      }
      __builtin_amdgcn_s_setprio(1);
      #pragma unroll
      for (int m = 0; m < 4; m++)
        #pragma unroll
        for (int n = 0; n < 2; n++)
          acc[m][n] = __builtin_amdgcn_mfma_f32_16x16x32_bf16(a[m], b[n], acc[m][n], 0, 0, 0);
      __builtin_amdgcn_s_setprio(0);
    }
  };
  auto compute = [&](int T) {
    const int b0 = (T & 1) * 32768;
    compute_sub(b0);
    compute_sub(b0 + 16384);
  };

  // prologue: both buffers issued; wait for buf0 (8 loads of stage(1) in flight)
  stage(0); stage(1);
  asm volatile("s_waitcnt vmcnt(8)" ::: "memory");
  __builtin_amdgcn_s_barrier();

  for (int t = 0; t < K3_NT; ++t) {
    compute(t);
    __builtin_amdgcn_s_barrier();            // all waves done reading buf[t&1]
    if (t + 2 < K3_NT) {
      stage(t + 2);                          // refill buf[t&1]
      asm volatile("s_waitcnt vmcnt(8)" ::: "memory");  // stage(t+1) done
    } else {
      asm volatile("s_waitcnt vmcnt(0)" ::: "memory");  // drain tail
    }
    __builtin_amdgcn_s_barrier();            // buf[(t+1)&1] ready
  }

  // epilogue: plain vector stores to this ci-half's partial buffer
  float* outP = h ? out1 : out0;
  const int r16 = l & 15;
  const int hi = l >> 4;
  #pragma unroll
  for (int m = 0; m < 4; m++) {
    const int xr = wm * 64 + m * 16 + hi * 4;
    #pragma unroll
    for (int n = 0; n < 2; n++) {
      const int co = wn * 32 + n * 16 + r16;
      *reinterpret_cast<f32x4*>(&outP[((size_t)co << 14) + (z << 7) + xr]) = acc[m][n];
    }
  }
}

// ============ K4: fused split-K reduce + per-channel LN + exact GELU ============
__device__ __forceinline__ float gelu_exact(float x) {
  return 0.5f * x * (1.0f + erff(x * 0.70710678118654752440f));
}

__global__ __launch_bounds__(256) void k4_ln(const float* __restrict__ c0,
                                             const float* __restrict__ c1,
                                             float* __restrict__ outp) {
  const int co = blockIdx.x;
  const float4* p0 = reinterpret_cast<const float4*>(c0 + ((size_t)co << 14));
  const float4* p1 = reinterpret_cast<const float4*>(c1 + ((size_t)co << 14));
  float4 v[16];
  float s = 0.f, s2 = 0.f;
  #pragma unroll
  for (int i = 0; i < 16; i++) {
    float4 a = p0[threadIdx.x + (i << 8)];
    float4 b = p1[threadIdx.x + (i << 8)];
    float4 t;
    t.x = a.x + b.x; t.y = a.y + b.y; t.z = a.z + b.z; t.w = a.w + b.w;
    v[i] = t;
    s  += t.x + t.y + t.z + t.w;
    s2 += t.x * t.x + t.y * t.y + t.z * t.z + t.w * t.w;
  }
  #pragma unroll
  for (int off = 32; off > 0; off >>= 1) {
    s  += __shfl_down(s, off);
    s2 += __shfl_down(s2, off);
  }
  __shared__ float red[8];
  __shared__ float mb[2];
  const int wv = threadIdx.x >> 6, ln = threadIdx.x & 63;
  if (ln == 0) { red[wv] = s; red[wv + 4] = s2; }
  __syncthreads();
  if (threadIdx.x == 0) {
    float S  = red[0] + red[1] + red[2] + red[3];
    float S2 = red[4] + red[5] + red[6] + red[7];
    float mu = S * (1.0f / 16384.0f);
    float var = S2 * (1.0f / 16384.0f) - mu * mu;
    mb[0] = mu;
    mb[1] = 1.0f / sqrtf(var + 1e-5f);
  }
  __syncthreads();
  const float mu = mb[0], inv = mb[1];
  float4* op = reinterpret_cast<float4*>(outp + ((size_t)co << 14));
  #pragma unroll
  for (int i = 0; i < 16; i++) {
    float4 t = v[i];
    float4 r;
    r.x = gelu_exact((t.x - mu) * inv);
    r.y = gelu_exact((t.y - mu) * inv);
    r.z = gelu_exact((t.z - mu) * inv);
    r.w = gelu_exact((t.w - mu) * inv);
    op[threadIdx.x + (i << 8)] = r;
  }
}

extern "C" void kernel_launch(void* const* d_in, const int* in_sizes, int n_in,
                              void* d_out, int out_size, void* d_ws, size_t ws_size,
                              hipStream_t stream) {
  const float* cam_feat = (const float*)d_in[0];
  const float* cam2ego  = (const float*)d_in[1];
  const float* intr     = (const float*)d_in[2];
  const float* conv_w   = (const float*)d_in[3];
  float* out = (float*)d_out;
  char* ws = (char*)d_ws;

  float*          P     = (float*)(ws + OFF_P);
  __hip_bfloat16* Wp    = (__hip_bfloat16*)(ws + OFF_W);
  __hip_bfloat16* camT  = (__hip_bfloat16*)(ws + OFF_CAMT);
  __hip_bfloat16* F     = (__hip_bfloat16*)(ws + OFF_F);
  float*          conv0 = (float*)(ws + OFF_CONV);
  float*          conv1 = (float*)(ws + OFF_CAMT);  // camT slot is dead after k2

  hipLaunchKernelGGL(k0_mats, dim3(1), dim3(64), 0, stream, cam2ego, intr, P);
  hipLaunchKernelGGL(k1_transpose, dim3(NCAM * HF * 4), dim3(128), 0, stream, cam_feat, camT);
  hipLaunchKernelGGL(k1b_packw, dim3(512), dim3(256), 0, stream, conv_w, Wp);
  hipLaunchKernelGGL(k2_sample, dim3(130 * 130), dim3(256), 0, stream, camT, P, F);
  hipLaunchKernelGGL(k3_gemm, dim3(256), dim3(512), 0, stream, F, Wp, conv0, conv1);
  hipLaunchKernelGGL(k4_ln, dim3(128), dim3(256), 0, stream, conv0, conv1, out);
}